// Round 1
// baseline (1169.226 us; speedup 1.0000x reference)
//
#include <hip/hip_runtime.h>
#include <math.h>

// Problem constants (fixed by the reference)
#define N_NODES 100000
#define N_EDGES 1600000
#define NFEAT 128
#define NHID  64
#define NCLASS 40
#define NL 6

__device__ __forceinline__ float rdlane(float v, int l) {
  return __int_as_float(__builtin_amdgcn_readlane(__float_as_int(v), l));
}

// ---------------------------------------------------------------------------
// CSR build: histogram -> exclusive scan -> scatter (packed {col, val})
// ---------------------------------------------------------------------------
__global__ void zero_cnt_k(int* __restrict__ cnt) {
  int i = blockIdx.x * 256 + threadIdx.x;
  if (i < N_NODES) cnt[i] = 0;
}

__global__ void hist_k(const int* __restrict__ row, int* __restrict__ cnt) {
  int e = blockIdx.x * 256 + threadIdx.x;
  if (e < N_EDGES) atomicAdd(&cnt[row[e]], 1);
}

__global__ __launch_bounds__(1024) void scan1_k(const int* __restrict__ cnt,
                                                int* __restrict__ rp,
                                                int* __restrict__ bsum) {
  __shared__ int sd[1024];
  int t = threadIdx.x;
  int idx = blockIdx.x * 1024 + t;
  int v = (idx < N_NODES) ? cnt[idx] : 0;
  sd[t] = v;
  __syncthreads();
  for (int off = 1; off < 1024; off <<= 1) {
    int add = (t >= off) ? sd[t - off] : 0;
    __syncthreads();
    sd[t] += add;
    __syncthreads();
  }
  if (idx < N_NODES) rp[idx] = sd[t] - v;   // exclusive
  if (t == 0) bsum[blockIdx.x] = sd[1023];  // block total
}

__global__ void scan2_k(int* __restrict__ bsum, int nb) {
  if (threadIdx.x == 0 && blockIdx.x == 0) {
    int run = 0;
    for (int i = 0; i < nb; ++i) { int x = bsum[i]; bsum[i] = run; run += x; }
  }
}

__global__ void scan3_k(int* __restrict__ rp, int* __restrict__ cur,
                        const int* __restrict__ bsum) {
  int i = blockIdx.x * 256 + threadIdx.x;
  if (i < N_NODES) {
    int v = rp[i] + bsum[i >> 10];
    rp[i] = v;
    cur[i] = v;  // scatter cursor starts at row base
  }
  if (i == 0) rp[N_NODES] = N_EDGES;
}

__global__ void scatter_k(const int* __restrict__ row, const int* __restrict__ col,
                          const float* __restrict__ val, int* __restrict__ cur,
                          int2* __restrict__ ep) {
  int e = blockIdx.x * 256 + threadIdx.x;
  if (e < N_EDGES) {
    int r = row[e];
    int p = atomicAdd(&cur[r], 1);
    ep[p] = make_int2(col[e], __float_as_int(val[e]));
  }
}

// ---------------------------------------------------------------------------
// GEMM: H[N,K] @ W[K,COLS] -> S[N,COLS].  Wave-per-8-rows; full W column in
// VGPRs per lane; H values broadcast via v_readlane (constant lane index after
// full unroll) so the inner loop is pure FMA + readlane. No LDS, no barriers.
// ---------------------------------------------------------------------------
template <int K, int COLS>
__global__ __launch_bounds__(256) void gemm_rl(const float* __restrict__ H,
                                               const float* __restrict__ W,
                                               float* __restrict__ S) {
  const int lane = threadIdx.x & 63;
  constexpr int KW = K / 64;

  float wreg[K];
#pragma unroll
  for (int k = 0; k < K; ++k)
    wreg[k] = (COLS == 64 || lane < COLS) ? W[k * COLS + lane] : 0.0f;

  const int nrg = N_NODES / 8;  // 12500 row-groups of 8
  for (int rg = blockIdx.x * 4 + (threadIdx.x >> 6); rg < nrg; rg += gridDim.x * 4) {
    const int r0 = rg * 8;
    float hreg[8][KW];
#pragma unroll
    for (int i = 0; i < 8; ++i)
#pragma unroll
      for (int p = 0; p < KW; ++p)
        hreg[i][p] = H[(size_t)(r0 + i) * K + p * 64 + lane];

    float acc[8];
#pragma unroll
    for (int i = 0; i < 8; ++i) acc[i] = 0.0f;

#pragma unroll
    for (int p = 0; p < KW; ++p)
#pragma unroll
      for (int k = 0; k < 64; ++k) {
        const float w = wreg[p * 64 + k];
#pragma unroll
        for (int i = 0; i < 8; ++i)
          acc[i] = fmaf(rdlane(hreg[i][p], k), w, acc[i]);
      }

    if (COLS == 64 || lane < COLS) {
#pragma unroll
      for (int i = 0; i < 8; ++i)
        S[(size_t)(r0 + i) * COLS + lane] = acc[i];
    }
  }
}

// ---------------------------------------------------------------------------
// SpMM (CSR, atomic-free): wave per node, lane = feature (64 wide).
// agg[node][lane] = sum_e val_e * S[col_e][lane]; fused bias/ReLU/residual.
// Edge records loaded wave-uniform (HW broadcasts the identical address).
// ---------------------------------------------------------------------------
template <bool RELU, bool RES>
__global__ __launch_bounds__(256) void spmm64_k(const float* __restrict__ S,
                                                const int2* __restrict__ ep,
                                                const int* __restrict__ rp,
                                                const float* __restrict__ bias,
                                                const float* __restrict__ res,
                                                float* __restrict__ out) {
  const int lane = threadIdx.x & 63;
  const int node = blockIdx.x * 4 + (threadIdx.x >> 6);
  const int start = rp[node], end = rp[node + 1];

  float a0 = 0.0f, a1 = 0.0f;
  int e = start;
  for (; e + 4 <= end; e += 4) {
    int2 e0 = ep[e + 0], e1 = ep[e + 1], e2 = ep[e + 2], e3 = ep[e + 3];
    a0 = fmaf(__int_as_float(e0.y), S[(size_t)e0.x * 64 + lane], a0);
    a1 = fmaf(__int_as_float(e1.y), S[(size_t)e1.x * 64 + lane], a1);
    a0 = fmaf(__int_as_float(e2.y), S[(size_t)e2.x * 64 + lane], a0);
    a1 = fmaf(__int_as_float(e3.y), S[(size_t)e3.x * 64 + lane], a1);
  }
  for (; e < end; ++e) {
    int2 ee = ep[e];
    a0 = fmaf(__int_as_float(ee.y), S[(size_t)ee.x * 64 + lane], a0);
  }

  float r = a0 + a1 + bias[lane];
  if (RELU) r = fmaxf(r, 0.0f);
  if (RES) r += res[(size_t)node * 64 + lane];
  out[(size_t)node * 64 + lane] = r;
}

// Final layer: SpMM (40-wide) + bias + log_softmax fused, writes d_out.
__global__ __launch_bounds__(256) void spmm_final_k(const float* __restrict__ S40,
                                                    const int2* __restrict__ ep,
                                                    const int* __restrict__ rp,
                                                    const float* __restrict__ b2,
                                                    float* __restrict__ out) {
  const int lane = threadIdx.x & 63;
  const int node = blockIdx.x * 4 + (threadIdx.x >> 6);
  const int start = rp[node], end = rp[node + 1];

  float a0 = 0.0f, a1 = 0.0f;
  int e = start;
  for (; e + 2 <= end; e += 2) {
    int2 e0 = ep[e], e1 = ep[e + 1];
    // lanes >= 40 read slightly past row end but stay inside the S buffer;
    // their values are never used (masked out of reductions & store).
    a0 = fmaf(__int_as_float(e0.y), S40[(size_t)e0.x * 40 + lane], a0);
    a1 = fmaf(__int_as_float(e1.y), S40[(size_t)e1.x * 40 + lane], a1);
  }
  for (; e < end; ++e) {
    int2 ee = ep[e];
    a0 = fmaf(__int_as_float(ee.y), S40[(size_t)ee.x * 40 + lane], a0);
  }

  float logit = a0 + a1 + ((lane < NCLASS) ? b2[lane] : 0.0f);
  float mx = (lane < NCLASS) ? logit : -INFINITY;
#pragma unroll
  for (int off = 32; off; off >>= 1) mx = fmaxf(mx, __shfl_xor(mx, off));
  float ex = (lane < NCLASS) ? expf(logit - mx) : 0.0f;
  float sum = ex;
#pragma unroll
  for (int off = 32; off; off >>= 1) sum += __shfl_xor(sum, off);
  if (lane < NCLASS) out[(size_t)node * NCLASS + lane] = logit - mx - logf(sum);
}

// ---------------------------------------------------------------------------
extern "C" void kernel_launch(void* const* d_in, const int* in_sizes, int n_in,
                              void* d_out, int out_size, void* d_ws, size_t ws_size,
                              hipStream_t stream) {
  const float* x    = (const float*)d_in[0];
  const int*   erow = (const int*)d_in[1];
  const int*   ecol = (const int*)d_in[2];
  const float* eval = (const float*)d_in[3];
  const float* W1   = (const float*)d_in[4];
  const float* b1   = (const float*)d_in[5];
  const float* Wm   = (const float*)d_in[6];
  const float* bm   = (const float*)d_in[7];
  const float* W2   = (const float*)d_in[8];
  const float* b2   = (const float*)d_in[9];
  float* out = (float*)d_out;

  // Workspace layout (~90.4 MB total)
  char* ws = (char*)d_ws;
  size_t off = 0;
  auto alloc = [&](size_t bytes) {
    void* p = ws + off;
    off = (off + bytes + 255) & ~(size_t)255;
    return p;
  };
  int*   rp   = (int*)alloc((N_NODES + 1) * sizeof(int));
  int*   cur  = (int*)alloc(N_NODES * sizeof(int));       // counts, then cursors
  int*   bsum = (int*)alloc(128 * sizeof(int));
  int2*  ep   = (int2*)alloc((size_t)N_EDGES * sizeof(int2));
  float* S    = (float*)alloc((size_t)N_NODES * 64 * sizeof(float));
  float* buf0 = (float*)alloc((size_t)N_NODES * 64 * sizeof(float));
  float* buf1 = (float*)alloc((size_t)N_NODES * 64 * sizeof(float));

  const int ZB = (N_NODES + 255) / 256;   // 391
  const int EB = N_EDGES / 256;           // 6250 (exact)
  const int SB = (N_NODES + 1023) / 1024; // 98
  const int GEMM_GRID = 1024;
  const int SPMM_GRID = N_NODES / 4;      // 25000 (exact)

  // CSR build (same adjacency reused by all 8 layers)
  zero_cnt_k<<<ZB, 256, 0, stream>>>(cur);
  hist_k<<<EB, 256, 0, stream>>>(erow, cur);
  scan1_k<<<SB, 1024, 0, stream>>>(cur, rp, bsum);
  scan2_k<<<1, 64, 0, stream>>>(bsum, SB);
  scan3_k<<<ZB, 256, 0, stream>>>(rp, cur, bsum);
  scatter_k<<<EB, 256, 0, stream>>>(erow, ecol, eval, cur, ep);

  // Layer 1: h1 = relu(A @ (x@W1) + b1) -> buf0
  gemm_rl<128, 64><<<GEMM_GRID, 256, 0, stream>>>(x, W1, S);
  spmm64_k<true, false><<<SPMM_GRID, 256, 0, stream>>>(S, ep, rp, b1, nullptr, buf0);

  // Layer 2 (Wm[0]): h2 = relu(A @ (h1@Wm0) + bm0) -> buf1  (no residual)
  gemm_rl<64, 64><<<GEMM_GRID, 256, 0, stream>>>(buf0, Wm, S);
  spmm64_k<true, false><<<SPMM_GRID, 256, 0, stream>>>(S, ep, rp, bm, nullptr, buf1);

  // Layers 3..7 (Wm[1..5]): h = relu(A @ (prev@Wmk) + bmk) + prev2
  float* prev2 = buf0;
  float* prev  = buf1;
  for (int k = 1; k < NL; ++k) {
    gemm_rl<64, 64><<<GEMM_GRID, 256, 0, stream>>>(prev, Wm + (size_t)k * 64 * 64, S);
    float* ob = prev2;  // overwrite prev2's buffer (read & write same index per thread)
    spmm64_k<true, true><<<SPMM_GRID, 256, 0, stream>>>(S, ep, rp, bm + k * 64, prev2, ob);
    prev2 = prev;
    prev  = ob;
  }

  // Final: out = log_softmax(A @ (prev@W2) + b2)
  gemm_rl<64, 40><<<GEMM_GRID, 256, 0, stream>>>(prev, W2, S);
  spmm_final_k<<<SPMM_GRID, 256, 0, stream>>>(S, ep, rp, b2, out);
}